// Round 6
// baseline (122.833 us; speedup 1.0000x reference)
//
#include <hip/hip_runtime.h>
#include <math.h>

// Wave-independent span IIR (z-formulation):
//   z[i] = alpha*z[i-1] + d[i];  y[i] = d[i] - (1-alpha)*z[i-1]
// R6: remove ALL block-level coupling. R1/R3/R4/R5 (four barrier/pipeline
// structures) all plateau ~33us; the last invariant is block lockstep from
// the cross-wave carry compose. Here each WAVE owns a private span of 8192
// outputs + its own 2048-elem halo: no __syncthreads, no s_barrier, no LDS.
// Per-wave 2-deep register pipeline: while chunk c computes, chunk c+2
// loads; d,mx kept in regs so the x-buffer is fully consumed in phase A
// (prefetch distance = 2 chunks ~= 2 iteration times > HBM latency).
// Waves drift freely -> reads/stores/VALU from 8 waves/CU interleave
// continuously instead of bursting in phase.
// Cost: halo amp 25% (+16MB reads ~ +2.5us at BW ceiling) for zero convoy.
// 2048 waves = 8/CU = 2/SIMD; VGPR<=128 via (256,2); static-indexed
// register arrays only (parity-paired loop, rule #20).
#define TPB 256
#define WSPAN 8192                // output elems per wave
#define WCHUNK 1024               // elems per chunk (lane: 4 runs of 4)
#define NCH (WSPAN / WCHUNK)      // 8 chunks per span
#define HALO 2048                 // alpha^2048 ~ 2.9e-3 << 0.1075 threshold

typedef float v4f __attribute__((ext_vector_type(4)));

template<int CTRL, int RM, int BM, bool BC>
__device__ __forceinline__ float dppf(float v) {
    return __int_as_float(__builtin_amdgcn_update_dpp(
        0, __float_as_int(v), CTRL, RM, BM, BC));
}

__device__ __forceinline__ float readlane_f(float v, int l) {
    return __int_as_float(__builtin_amdgcn_readlane(__float_as_int(v), l));
}

// Weighted inclusive scan over 64 lanes: S_l = sum_{k<=l} m^(l-k) * v_k, m=A4.
// row_shr 1/2/4/8 (within-16), row_bcast:15 (rows 1,3 += w1 * prev-row
// prefix), row_bcast:31 (rows 2,3 += w2 * S_31).
__device__ __forceinline__ float scan_iir(float v, float mo1, float mo2,
                                          float mo4, float mo8,
                                          float w1, float w2) {
    float b;
    b = dppf<0x111, 0xF, 0xF, true >(v); v = fmaf(mo1, b, v); // row_shr:1
    b = dppf<0x112, 0xF, 0xF, true >(v); v = fmaf(mo2, b, v); // row_shr:2
    b = dppf<0x114, 0xF, 0xF, true >(v); v = fmaf(mo4, b, v); // row_shr:4
    b = dppf<0x118, 0xF, 0xF, true >(v); v = fmaf(mo8, b, v); // row_shr:8
    b = dppf<0x142, 0xA, 0xF, false>(v); v = fmaf(w1,  b, v); // row_bcast:15
    b = dppf<0x143, 0xC, 0xF, false>(v); v = fmaf(w2,  b, v); // row_bcast:31
    return v;
}

__device__ __forceinline__ float shape(float xs, int ty, float g, float dc,
                                       float c1, float c0) {
    if (ty == 0) {
        // tanh(p) = 1 - 2/(exp(2p)+1), exp folded: e2 = 2^(xs*c1 + c0)
        float e2 = __builtin_amdgcn_exp2f(fmaf(xs, c1, c0));
        return fmaf(-2.0f, __builtin_amdgcn_rcpf(e2 + 1.0f), 1.0f);
    }
    float p = (xs + dc) * g;
    if (ty == 1) {
        return fminf(fmaxf(p, -1.0f), 1.0f);
    } else if (ty == 2) {
        float r = p + 1.0f;
        float rem = r - 4.0f * floorf(r * 0.25f);   // jnp.remainder(r, 4)
        return fabsf(rem - 2.0f) - 1.0f;
    } else if (ty == 3) {
        return __sinf(p * 1.5707963267948966f);
    } else {
        return p / (1.0f + fabsf(p));
    }
}

__device__ __forceinline__ void load_chunk(v4f (&xv)[4],
                                           const float* __restrict__ xr,
                                           int base, int lo, int N) {
    #pragma unroll
    for (int s = 0; s < 4; ++s) {
        const int j = base + s * 256 + lo;
        if (j + 4 <= N) {
            xv[s] = *reinterpret_cast<const v4f*>(xr + j);
        } else {
            xv[s].x = (j + 0 < N) ? xr[j + 0] : 0.0f;
            xv[s].y = (j + 1 < N) ? xr[j + 1] : 0.0f;
            xv[s].z = (j + 2 < N) ? xr[j + 2] : 0.0f;
            xv[s].w = (j + 3 < N) ? xr[j + 3] : 0.0f;
        }
    }
}

// total z-contribution of a 1024-elem chunk (lane-parallel, in-wave only)
__device__ __forceinline__ float chunk_total(
    const v4f (&h)[4], int ty, float g, float dc, float c1, float c0,
    float alpha, float A4, float A8, float A16, float A32, float A256,
    float w1, float w2)
{
    float tot = 0.0f;
    #pragma unroll
    for (int s = 0; s < 4; ++s) {
        float acc = shape(h[s].x, ty, g, dc, c1, c0);
        acc = fmaf(alpha, acc, shape(h[s].y, ty, g, dc, c1, c0));
        acc = fmaf(alpha, acc, shape(h[s].z, ty, g, dc, c1, c0));
        acc = fmaf(alpha, acc, shape(h[s].w, ty, g, dc, c1, c0));
        const float sc = scan_iir(acc, A4, A8, A16, A32, w1, w2);
        const float T  = readlane_f(sc, 63);
        tot = (s == 0) ? T : fmaf(A256, tot, T);
    }
    return tot;
}

// One chunk: phase A (shape+scan, buffer fully consumed), prefetch chunk
// c+2 into the SAME buffer, phase C (output from d/mx regs + nt stores).
// Returns the carry after this chunk. All arrays statically indexed.
__device__ __forceinline__ float step_chunk(
    v4f (&cur)[4], int c, int cEnd, float carry,
    const float* __restrict__ xr, float* __restrict__ outr,
    int spanStart, int lo, int N,
    int ty, float g, float dc, float c1, float c0,
    float alpha, float beta, float mm, float om,
    float A4, float A8, float A16, float A32, float A256,
    float w1, float w2, float apl)
{
    // ---- phase A: d = shape(x), mx = om*x, run summaries + wave scans ----
    v4f d4[4], mx4[4];
    float iv[4], Tk[4];
    #pragma unroll
    for (int s = 0; s < 4; ++s) {
        d4[s].x = shape(cur[s].x, ty, g, dc, c1, c0); mx4[s].x = om * cur[s].x;
        d4[s].y = shape(cur[s].y, ty, g, dc, c1, c0); mx4[s].y = om * cur[s].y;
        d4[s].z = shape(cur[s].z, ty, g, dc, c1, c0); mx4[s].z = om * cur[s].z;
        d4[s].w = shape(cur[s].w, ty, g, dc, c1, c0); mx4[s].w = om * cur[s].w;
        float acc = d4[s].x;
        acc = fmaf(alpha, acc, d4[s].y);
        acc = fmaf(alpha, acc, d4[s].z);
        acc = fmaf(alpha, acc, d4[s].w);
        iv[s] = scan_iir(acc, A4, A8, A16, A32, w1, w2);
        Tk[s] = readlane_f(iv[s], 63);
    }

    // ---- prefetch chunk c+2 into the just-consumed buffer (2-deep) ----
    if (c + 2 < cEnd)
        load_chunk(cur, xr, spanStart + (c + 2) * WCHUNK, lo, N);

    // ---- phase C: y[i] = d[i] - beta*z[i-1]; out = mx + mm*y ----
    float C = carry;                          // z entering sub-block s
    #pragma unroll
    for (int s = 0; s < 4; ++s) {
        const int j = spanStart + c * WCHUNK + s * 256 + lo;
        // exclusive lane scan = previous lane's inclusive (lane0 -> 0)
        const float ex = dppf<0x138, 0xF, 0xF, true>(iv[s]); // wave_shr:1
        float z = fmaf(apl, C, ex);           // z before this lane's run
        v4f ov; float y;
        y = fmaf(-beta, z, d4[s].x); ov.x = fmaf(mm, y, mx4[s].x); z = fmaf(alpha, z, d4[s].x);
        y = fmaf(-beta, z, d4[s].y); ov.y = fmaf(mm, y, mx4[s].y); z = fmaf(alpha, z, d4[s].y);
        y = fmaf(-beta, z, d4[s].z); ov.z = fmaf(mm, y, mx4[s].z); z = fmaf(alpha, z, d4[s].z);
        y = fmaf(-beta, z, d4[s].w); ov.w = fmaf(mm, y, mx4[s].w);
        if (j + 4 <= N) {
            __builtin_nontemporal_store(ov, reinterpret_cast<v4f*>(outr + j));
        } else {
            if (j + 0 < N) outr[j + 0] = ov.x;
            if (j + 1 < N) outr[j + 1] = ov.y;
            if (j + 2 < N) outr[j + 2] = ov.z;
            if (j + 3 < N) outr[j + 3] = ov.w;
        }
        C = fmaf(A256, C, Tk[s]);             // z entering next sub-block
    }
    return C;                                 // carry after this chunk
}

__global__ void __launch_bounds__(TPB, 2)
dist_kernel(const float* __restrict__ x,
            const float* __restrict__ drive,
            const float* __restrict__ bias,
            const float* __restrict__ mix,
            const int* __restrict__ type_idx,
            float* __restrict__ out,
            int N, float alpha, float beta)
{
    const int row  = blockIdx.y;
    const int tid  = threadIdx.x;
    const int lane = tid & 63;
    const int wv   = tid >> 6;
    const int ty   = *type_idx;                       // wave-uniform

    const int spanStart = (blockIdx.x * (TPB / 64) + wv) * WSPAN;
    if (spanStart >= N) return;                       // per-wave exit: no syncs

    const long long rowBase = (long long)row * (long long)N;
    const float* __restrict__ xr = x + rowBase;
    float* __restrict__ outr = out + rowBase;

    const int lo = lane * 4;
    const int cEnd = min(NCH, (N - spanStart + WCHUNK - 1) / WCHUNK);

    // ---- issue halo loads first (oldest), then chunk 0/1 (keep flying) ----
    v4f h0[4], h1[4], bufA[4], bufB[4];
    const bool haveHalo = (spanStart > 0);            // wave-uniform
    if (haveHalo) {                                   // halo fully in-bounds
        load_chunk(h0, xr, spanStart - HALO,          lo, N);
        load_chunk(h1, xr, spanStart - HALO + WCHUNK, lo, N);
    }
    load_chunk(bufA, xr, spanStart,          lo, N);
    if (cEnd > 1) load_chunk(bufB, xr, spanStart + WCHUNK, lo, N);

    // ---- row params + constants (overlap with load flight) ----
    const float g  = exp2f(drive[row] * 7.972672880099267f);  // 10^(2.4*drive)
    const float dc = bias[row] * 2.0f - 1.0f;
    const float mm = mix[row];
    const float om = 1.0f - mm;
    const float c1 = g * 2.8853900817779268f;   // 2*log2(e)*g
    const float c0 = dc * c1;

    const float A2 = alpha * alpha;
    const float A4 = A2 * A2;
    const float A8 = A4 * A4;
    const float A16 = A8 * A8;
    const float A32 = A16 * A16;
    const float A64 = A32 * A32;
    const float A128 = A64 * A64;
    const float A256 = A128 * A128;
    const float A512 = A256 * A256;
    const float A1024 = A512 * A512;

    // per-lane multipliers: p15 = A4^(lane&15), apl = A4^lane
    float p15 = 1.0f;
    {
        float b = A4; const int n = lane & 15;
        #pragma unroll
        for (int i = 0; i < 4; ++i) { if ((n >> i) & 1) p15 *= b; b *= b; }
    }
    const float p31 = (lane & 16) ? p15 * A64  : p15;   // A4^(lane&31)
    const float apl = (lane & 32) ? p31 * A128 : p31;   // A4^lane
    const float w1 = A4 * p15;                          // A4^((lane&15)+1)
    const float w2 = A4 * p31;                          // A4^((lane&31)+1)

    // ---- halo: carry entering the span (waits h0/h1 only; c0/c1 fly) ----
    float carry = 0.0f;
    if (haveHalo) {
        carry = chunk_total(h0, ty, g, dc, c1, c0, alpha,
                            A4, A8, A16, A32, A256, w1, w2);
        const float t1 = chunk_total(h1, ty, g, dc, c1, c0, alpha,
                                     A4, A8, A16, A32, A256, w1, w2);
        carry = fmaf(A1024, carry, t1);
    }

    // ---- parity-paired main loop: all register arrays statically indexed ----
    for (int c = 0; c < cEnd; c += 2) {
        carry = step_chunk(bufA, c, cEnd, carry, xr, outr, spanStart, lo, N,
                           ty, g, dc, c1, c0, alpha, beta, mm, om,
                           A4, A8, A16, A32, A256, w1, w2, apl);
        if (c + 1 < cEnd)
            carry = step_chunk(bufB, c + 1, cEnd, carry, xr, outr, spanStart,
                               lo, N, ty, g, dc, c1, c0, alpha, beta, mm, om,
                               A4, A8, A16, A32, A256, w1, w2, apl);
    }
    // stores drain as the wave retires (no trailing waits)
}

extern "C" void kernel_launch(void* const* d_in, const int* in_sizes, int n_in,
                              void* d_out, int out_size, void* d_ws, size_t ws_size,
                              hipStream_t stream) {
    const float* x     = (const float*)d_in[0];
    const float* drive = (const float*)d_in[1];
    const float* bias  = (const float*)d_in[2];
    const float* mixp  = (const float*)d_in[3];
    const int*   tyi   = (const int*)d_in[4];
    float* out = (float*)d_out;

    const int B = in_sizes[1];              // drive is (B,1)
    const int N = in_sizes[0] / B;

    const double alpha_d = exp(-2.0 * M_PI * 20.0 / 44100.0);
    const float alpha = (float)alpha_d;
    const float beta  = (float)(1.0 - alpha_d);

    const int nSpans = (N + WSPAN - 1) / WSPAN;           // wave-spans per row
    const int wpb = TPB / 64;                             // waves per block
    dim3 grid((nSpans + wpb - 1) / wpb, B);
    dist_kernel<<<grid, TPB, 0, stream>>>(x, drive, bias, mixp, tyi, out, N, alpha, beta);
}

// Round 7
// 120.469 us; speedup vs baseline: 1.0196x; 1.0196x over previous
//
#include <hip/hip_runtime.h>
#include <math.h>

// One-shot span parallel IIR (z-formulation):
//   z[i] = alpha*z[i-1] + d[i];  y[i] = d[i] - (1-alpha)*z[i-1]
// Best-known structure (R4, kernel ~32.3us): each block does ONE span,
// exactly 2 barriers, stores last:
//   stage span+halo (global_load_lds burst) -> barrier -> halo scan + wave
//   scans (VALU/DPP on LDS) -> barrier -> compose + phase C + stores -> end.
// R7 (two levers on the R4 base, counter-distinguishable):
//  1. PLAIN stores instead of nontemporal: nt forced all 65.5MB to stream
//     synchronously to HBM inside the kernel (WRITE_SIZE==output exactly);
//     plain stores land in L2/L3 writeback and flush under the next
//     dispatch. Reads are already ~40% L3-served (R4 FETCH 40.8MB < 67MB
//     input) -- let writes use the 256MB L3 symmetrically.
//  2. launch_bounds(512,8): VGPR=16, so lift the regalloc hint cap and let
//     the LDS limit (4 blocks/CU = 32 waves/CU = 100%) be the binding one.
// LDS = (8192+2048)*4 = 40960 B exactly -> 4 blocks/CU; scan totals live in
// dead halo slots to avoid LDS rounding past 40960.
// Grid = 32 x 64 = 2048 blocks = 2 exact resident rounds.
#define TPB 512
#define WAVES (TPB / 64)          // 8
#define SPAN 8192                 // output elems per block
#define HALO 2048                 // alpha^2048 ~ 2.9e-3 << 0.1075 threshold
#define TOT (SPAN + HALO)         // 10240 floats staged = 40960 B LDS
#define WSPAN (SPAN / WAVES)      // 1024 floats per wave = 4 sub-blocks of 256

typedef float v4f __attribute__((ext_vector_type(4)));

template<int CTRL, int RM, int BM, bool BC>
__device__ __forceinline__ float dppf(float v) {
    return __int_as_float(__builtin_amdgcn_update_dpp(
        0, __float_as_int(v), CTRL, RM, BM, BC));
}

__device__ __forceinline__ float readlane_f(float v, int l) {
    return __int_as_float(__builtin_amdgcn_readlane(__float_as_int(v), l));
}

// global -> LDS direct copy, 16B per lane. LDS dest is wave-uniform base
// (+ lane*16 by HW); global src is per-lane. Linear on both sides.
__device__ __forceinline__ void stage16(const float* __restrict__ g, float* l) {
    __builtin_amdgcn_global_load_lds(
        (const __attribute__((address_space(1))) unsigned int*)g,
        (__attribute__((address_space(3))) unsigned int*)l, 16, 0, 0);
}

// Weighted inclusive scan over 64 lanes: S_l = sum_{k<=l} m^(l-k) * v_k, m=A4.
// row_shr 1/2/4/8 (within-16 scan), row_bcast:15 (rows 1,3 += w1 * prev-row
// prefix), row_bcast:31 (rows 2,3 += w2 * S_31).
// w1 = m^((lane&15)+1), w2 = m^((lane&31)+1).
__device__ __forceinline__ float scan_iir(float v, float mo1, float mo2,
                                          float mo4, float mo8,
                                          float w1, float w2) {
    float b;
    b = dppf<0x111, 0xF, 0xF, true >(v); v = fmaf(mo1, b, v); // row_shr:1
    b = dppf<0x112, 0xF, 0xF, true >(v); v = fmaf(mo2, b, v); // row_shr:2
    b = dppf<0x114, 0xF, 0xF, true >(v); v = fmaf(mo4, b, v); // row_shr:4
    b = dppf<0x118, 0xF, 0xF, true >(v); v = fmaf(mo8, b, v); // row_shr:8
    b = dppf<0x142, 0xA, 0xF, false>(v); v = fmaf(w1,  b, v); // row_bcast:15
    b = dppf<0x143, 0xC, 0xF, false>(v); v = fmaf(w2,  b, v); // row_bcast:31
    return v;
}

__device__ __forceinline__ float shape(float xs, int ty, float g, float dc,
                                       float c1, float c0) {
    if (ty == 0) {
        // tanh(p) = 1 - 2/(exp(2p)+1), exp folded: e2 = 2^(xs*c1 + c0)
        float e2 = __builtin_amdgcn_exp2f(fmaf(xs, c1, c0));
        return fmaf(-2.0f, __builtin_amdgcn_rcpf(e2 + 1.0f), 1.0f);
    }
    float p = (xs + dc) * g;
    if (ty == 1) {
        return fminf(fmaxf(p, -1.0f), 1.0f);
    } else if (ty == 2) {
        float r = p + 1.0f;
        float rem = r - 4.0f * floorf(r * 0.25f);   // jnp.remainder(r, 4)
        return fabsf(rem - 2.0f) - 1.0f;
    } else if (ty == 3) {
        return __sinf(p * 1.5707963267948966f);
    } else {
        return p / (1.0f + fabsf(p));
    }
}

__global__ void __launch_bounds__(TPB, 8)
dist_kernel(const float* __restrict__ x,
            const float* __restrict__ drive,
            const float* __restrict__ bias,
            const float* __restrict__ mix,
            const int* __restrict__ type_idx,
            float* __restrict__ out,
            int N, float alpha, float beta)
{
    const int row  = blockIdx.y;
    const int bx   = blockIdx.x;
    const int tid  = threadIdx.x;
    const int lane = tid & 63;
    const int wv   = tid >> 6;
    const int ty   = *type_idx;   // wave-uniform

    const int spanStart = bx * SPAN;

    const long long rowBase = (long long)row * (long long)N;
    const float* __restrict__ xr = x + rowBase;
    float* __restrict__ outr = out + rowBase;

    // sbuf[p] mirrors x[spanStart - HALO + p]; halo part staged only if bx>0.
    __shared__ float sbuf[TOT];

    // ---- staging burst: deep queue of 1KB global_load_lds ----
    const bool fullSpan = (spanStart + SPAN <= N);
    if (fullSpan) {
        if (bx > 0) {                       // halo+span: 1280 floats/wave
            const int gb = spanStart - HALO + wv * (TOT / WAVES);
            const int lb = wv * (TOT / WAVES);
            #pragma unroll
            for (int i = 0; i < (TOT / WAVES) / 256; ++i)   // 5
                stage16(xr + gb + i * 256 + lane * 4, &sbuf[lb + i * 256]);
        } else {                            // span only: 1024 floats/wave
            const int gb = spanStart + wv * WSPAN;
            const int lb = HALO + wv * WSPAN;
            #pragma unroll
            for (int i = 0; i < WSPAN / 256; ++i)           // 4
                stage16(xr + gb + i * 256 + lane * 4, &sbuf[lb + i * 256]);
        }
    } else {
        // guarded fallback (partial span / small N): v4f-granular ds writes
        for (int p = tid * 4; p < TOT; p += TPB * 4) {
            const int j = spanStart - HALO + p;
            v4f v;
            v.x = (j + 0 >= 0 && j + 0 < N) ? xr[j + 0] : 0.0f;
            v.y = (j + 1 >= 0 && j + 1 < N) ? xr[j + 1] : 0.0f;
            v.z = (j + 2 >= 0 && j + 2 < N) ? xr[j + 2] : 0.0f;
            v.w = (j + 3 >= 0 && j + 3 < N) ? xr[j + 3] : 0.0f;
            *reinterpret_cast<v4f*>(&sbuf[p]) = v;
        }
    }

    // row params + constants (overlap with staging flight)
    const float g  = exp2f(drive[row] * 7.972672880099267f);  // 10^(2.4*drive)
    const float dc = bias[row] * 2.0f - 1.0f;
    const float mm = mix[row];
    const float om = 1.0f - mm;
    const float c1 = g * 2.8853900817779268f;   // 2*log2(e)*g
    const float c0 = dc * c1;

    const float A2 = alpha * alpha;
    const float A4 = A2 * A2;
    const float A8 = A4 * A4;
    const float A16 = A8 * A8;
    const float A32 = A16 * A16;
    const float A64 = A32 * A32;
    const float A128 = A64 * A64;
    const float A256 = A128 * A128;
    const float A512 = A256 * A256;
    const float A1024 = A512 * A512;

    // per-lane multipliers: p15 = A4^(lane&15), apl = A4^lane
    float p15 = 1.0f;
    {
        float b = A4; const int n = lane & 15;
        #pragma unroll
        for (int i = 0; i < 4; ++i) { if ((n >> i) & 1) p15 *= b; b *= b; }
    }
    const float p31 = (lane & 16) ? p15 * A64  : p15;   // A4^(lane&31)
    const float apl = (lane & 32) ? p31 * A128 : p31;   // A4^lane
    const float w1 = A4 * p15;                          // A4^((lane&15)+1)
    const float w2 = A4 * p31;                          // A4^((lane&31)+1)

    __syncthreads();   // (1) staging visible (drains global_load_lds)

    // ---- halo scan: wave w scans halo sub-block w (256 floats) ----
    // Th parked at sbuf[wv*256] — a slot this wave just finished reading;
    // no other wave reads the halo area, so no race. (bx==0: skipped, carry=0)
    if (bx > 0) {
        const v4f hx = *reinterpret_cast<const v4f*>(&sbuf[wv * 256 + lane * 4]);
        float r = shape(hx.x, ty, g, dc, c1, c0);
        r = fmaf(alpha, r, shape(hx.y, ty, g, dc, c1, c0));
        r = fmaf(alpha, r, shape(hx.z, ty, g, dc, c1, c0));
        r = fmaf(alpha, r, shape(hx.w, ty, g, dc, c1, c0));
        const float s = scan_iir(r, A4, A8, A16, A32, w1, w2);
        if (lane == 63) sbuf[wv * 256] = s;
    }

    // ---- span scans: wave w owns 1024 floats = 4 sub-blocks of 256 ----
    float iv[4], Tk[4];
    #pragma unroll
    for (int k = 0; k < 4; ++k) {
        const v4f xv = *reinterpret_cast<const v4f*>(
            &sbuf[HALO + wv * WSPAN + k * 256 + lane * 4]);
        float acc = shape(xv.x, ty, g, dc, c1, c0);
        acc = fmaf(alpha, acc, shape(xv.y, ty, g, dc, c1, c0));
        acc = fmaf(alpha, acc, shape(xv.z, ty, g, dc, c1, c0));
        acc = fmaf(alpha, acc, shape(xv.w, ty, g, dc, c1, c0));
        iv[k] = scan_iir(acc, A4, A8, A16, A32, w1, w2);
        Tk[k] = readlane_f(iv[k], 63);
    }
    const float Tw =
        fmaf(A256, fmaf(A256, fmaf(A256, Tk[0], Tk[1]), Tk[2]), Tk[3]);
    if (lane == 0) sbuf[wv * 256 + 1] = Tw;   // dead halo slot (own sub-block)
    __syncthreads();   // (2) totals visible; no stores issued yet

    // ---- compose: carry at spanStart, P = z entering this wave's region ----
    float carry = 0.0f;
    if (bx > 0) {
        #pragma unroll
        for (int w = 0; w < WAVES; ++w)
            carry = fmaf(A256, carry, sbuf[w * 256]);
    }
    float P = carry;
    for (int w = 0; w < wv; ++w) P = fmaf(A1024, P, sbuf[w * 256 + 1]);

    // ---- phase C: y[i] = d[i] - beta*z[i-1]; out = om*x + mm*y; stores last ----
    float S = 0.0f, aK = 1.0f;
    #pragma unroll
    for (int k = 0; k < 4; ++k) {
        const int j = spanStart + wv * WSPAN + k * 256 + lane * 4;
        const v4f xv = *reinterpret_cast<const v4f*>(
            &sbuf[HALO + wv * WSPAN + k * 256 + lane * 4]);
        const float d0 = shape(xv.x, ty, g, dc, c1, c0);
        const float d1 = shape(xv.y, ty, g, dc, c1, c0);
        const float d2 = shape(xv.z, ty, g, dc, c1, c0);
        const float d3 = shape(xv.w, ty, g, dc, c1, c0);
        const float Ck = fmaf(aK, P, S);              // z entering sub-block k
        // exclusive lane scan = previous lane's inclusive scan (lane0: 0)
        const float ex = dppf<0x138, 0xF, 0xF, true>(iv[k]); // wave_shr:1
        float z = fmaf(apl, Ck, ex);                  // z before lane's run
        v4f ov; float y;
        y = fmaf(-beta, z, d0); ov.x = fmaf(mm, y, om * xv.x); z = fmaf(alpha, z, d0);
        y = fmaf(-beta, z, d1); ov.y = fmaf(mm, y, om * xv.y); z = fmaf(alpha, z, d1);
        y = fmaf(-beta, z, d2); ov.z = fmaf(mm, y, om * xv.z); z = fmaf(alpha, z, d2);
        y = fmaf(-beta, z, d3); ov.w = fmaf(mm, y, om * xv.w);
        if (j + 4 <= N) {
            *reinterpret_cast<v4f*>(outr + j) = ov;   // plain store: L2/L3
        } else {
            if (j + 0 < N) outr[j + 0] = ov.x;
            if (j + 1 < N) outr[j + 1] = ov.y;
            if (j + 2 < N) outr[j + 2] = ov.z;
            if (j + 3 < N) outr[j + 3] = ov.w;
        }
        S = fmaf(A256, S, Tk[k]);
        aK *= A256;
    }
    // no trailing barrier: stores drain via L2/L3 writeback as block retires
}

extern "C" void kernel_launch(void* const* d_in, const int* in_sizes, int n_in,
                              void* d_out, int out_size, void* d_ws, size_t ws_size,
                              hipStream_t stream) {
    const float* x     = (const float*)d_in[0];
    const float* drive = (const float*)d_in[1];
    const float* bias  = (const float*)d_in[2];
    const float* mixp  = (const float*)d_in[3];
    const int*   tyi   = (const int*)d_in[4];
    float* out = (float*)d_out;

    const int B = in_sizes[1];              // drive is (B,1)
    const int N = in_sizes[0] / B;

    const double alpha_d = exp(-2.0 * M_PI * 20.0 / 44100.0);
    const float alpha = (float)alpha_d;
    const float beta  = (float)(1.0 - alpha_d);

    const int nSpans = (N + SPAN - 1) / SPAN;
    dim3 grid(nSpans, B);
    dist_kernel<<<grid, TPB, 0, stream>>>(x, drive, bias, mixp, tyi, out, N, alpha, beta);
}

// Round 8
// 118.374 us; speedup vs baseline: 1.0377x; 1.0177x over previous
//
#include <hip/hip_runtime.h>
#include <math.h>

// One-shot span parallel IIR (z-formulation):
//   z[i] = alpha*z[i-1] + d[i];  y[i] = d[i] - (1-alpha)*z[i-1]
// Best-known structure (R4, kernel ~32.3us): each block does ONE span,
// exactly 2 barriers, stores last:
//   stage span+halo (global_load_lds burst) -> barrier -> halo scan + wave
//   scans (VALU/DPP on LDS) -> barrier -> compose + phase C + nt-stores.
// R8 = R4 + launch_bounds(512,8) ONLY (isolated A/B; R7 confounded this
// with plain stores and regressed +4us — suspect: plain stores' L3 write
// allocation evicted the input's L3 residency that kept FETCH at 40.8MB).
//  * nontemporal stores RESTORED (no-allocate: writes bypass L3, input
//    stays L3-resident for the read stream).
//  * (512,8): VGPR=16, so the 6-wave/EU hint was the only cap at 3
//    blocks/CU; LDS (exactly 40960 B) permits 4 blocks/CU = 32 waves/CU.
// Grid = 32 x 64 = 2048 blocks = 2 exact resident rounds.
#define TPB 512
#define WAVES (TPB / 64)          // 8
#define SPAN 8192                 // output elems per block
#define HALO 2048                 // alpha^2048 ~ 2.9e-3 << 0.1075 threshold
#define TOT (SPAN + HALO)         // 10240 floats staged = 40960 B LDS
#define WSPAN (SPAN / WAVES)      // 1024 floats per wave = 4 sub-blocks of 256

typedef float v4f __attribute__((ext_vector_type(4)));

template<int CTRL, int RM, int BM, bool BC>
__device__ __forceinline__ float dppf(float v) {
    return __int_as_float(__builtin_amdgcn_update_dpp(
        0, __float_as_int(v), CTRL, RM, BM, BC));
}

__device__ __forceinline__ float readlane_f(float v, int l) {
    return __int_as_float(__builtin_amdgcn_readlane(__float_as_int(v), l));
}

// global -> LDS direct copy, 16B per lane. LDS dest is wave-uniform base
// (+ lane*16 by HW); global src is per-lane. Linear on both sides.
__device__ __forceinline__ void stage16(const float* __restrict__ g, float* l) {
    __builtin_amdgcn_global_load_lds(
        (const __attribute__((address_space(1))) unsigned int*)g,
        (__attribute__((address_space(3))) unsigned int*)l, 16, 0, 0);
}

// Weighted inclusive scan over 64 lanes: S_l = sum_{k<=l} m^(l-k) * v_k, m=A4.
// row_shr 1/2/4/8 (within-16 scan), row_bcast:15 (rows 1,3 += w1 * prev-row
// prefix), row_bcast:31 (rows 2,3 += w2 * S_31).
// w1 = m^((lane&15)+1), w2 = m^((lane&31)+1).
__device__ __forceinline__ float scan_iir(float v, float mo1, float mo2,
                                          float mo4, float mo8,
                                          float w1, float w2) {
    float b;
    b = dppf<0x111, 0xF, 0xF, true >(v); v = fmaf(mo1, b, v); // row_shr:1
    b = dppf<0x112, 0xF, 0xF, true >(v); v = fmaf(mo2, b, v); // row_shr:2
    b = dppf<0x114, 0xF, 0xF, true >(v); v = fmaf(mo4, b, v); // row_shr:4
    b = dppf<0x118, 0xF, 0xF, true >(v); v = fmaf(mo8, b, v); // row_shr:8
    b = dppf<0x142, 0xA, 0xF, false>(v); v = fmaf(w1,  b, v); // row_bcast:15
    b = dppf<0x143, 0xC, 0xF, false>(v); v = fmaf(w2,  b, v); // row_bcast:31
    return v;
}

__device__ __forceinline__ float shape(float xs, int ty, float g, float dc,
                                       float c1, float c0) {
    if (ty == 0) {
        // tanh(p) = 1 - 2/(exp(2p)+1), exp folded: e2 = 2^(xs*c1 + c0)
        float e2 = __builtin_amdgcn_exp2f(fmaf(xs, c1, c0));
        return fmaf(-2.0f, __builtin_amdgcn_rcpf(e2 + 1.0f), 1.0f);
    }
    float p = (xs + dc) * g;
    if (ty == 1) {
        return fminf(fmaxf(p, -1.0f), 1.0f);
    } else if (ty == 2) {
        float r = p + 1.0f;
        float rem = r - 4.0f * floorf(r * 0.25f);   // jnp.remainder(r, 4)
        return fabsf(rem - 2.0f) - 1.0f;
    } else if (ty == 3) {
        return __sinf(p * 1.5707963267948966f);
    } else {
        return p / (1.0f + fabsf(p));
    }
}

__global__ void __launch_bounds__(TPB, 8)
dist_kernel(const float* __restrict__ x,
            const float* __restrict__ drive,
            const float* __restrict__ bias,
            const float* __restrict__ mix,
            const int* __restrict__ type_idx,
            float* __restrict__ out,
            int N, float alpha, float beta)
{
    const int row  = blockIdx.y;
    const int bx   = blockIdx.x;
    const int tid  = threadIdx.x;
    const int lane = tid & 63;
    const int wv   = tid >> 6;
    const int ty   = *type_idx;   // wave-uniform

    const int spanStart = bx * SPAN;

    const long long rowBase = (long long)row * (long long)N;
    const float* __restrict__ xr = x + rowBase;
    float* __restrict__ outr = out + rowBase;

    // sbuf[p] mirrors x[spanStart - HALO + p]; halo part staged only if bx>0.
    __shared__ float sbuf[TOT];

    // ---- staging burst: deep queue of 1KB global_load_lds ----
    const bool fullSpan = (spanStart + SPAN <= N);
    if (fullSpan) {
        if (bx > 0) {                       // halo+span: 1280 floats/wave
            const int gb = spanStart - HALO + wv * (TOT / WAVES);
            const int lb = wv * (TOT / WAVES);
            #pragma unroll
            for (int i = 0; i < (TOT / WAVES) / 256; ++i)   // 5
                stage16(xr + gb + i * 256 + lane * 4, &sbuf[lb + i * 256]);
        } else {                            // span only: 1024 floats/wave
            const int gb = spanStart + wv * WSPAN;
            const int lb = HALO + wv * WSPAN;
            #pragma unroll
            for (int i = 0; i < WSPAN / 256; ++i)           // 4
                stage16(xr + gb + i * 256 + lane * 4, &sbuf[lb + i * 256]);
        }
    } else {
        // guarded fallback (partial span / small N): v4f-granular ds writes
        for (int p = tid * 4; p < TOT; p += TPB * 4) {
            const int j = spanStart - HALO + p;
            v4f v;
            v.x = (j + 0 >= 0 && j + 0 < N) ? xr[j + 0] : 0.0f;
            v.y = (j + 1 >= 0 && j + 1 < N) ? xr[j + 1] : 0.0f;
            v.z = (j + 2 >= 0 && j + 2 < N) ? xr[j + 2] : 0.0f;
            v.w = (j + 3 >= 0 && j + 3 < N) ? xr[j + 3] : 0.0f;
            *reinterpret_cast<v4f*>(&sbuf[p]) = v;
        }
    }

    // row params + constants (overlap with staging flight)
    const float g  = exp2f(drive[row] * 7.972672880099267f);  // 10^(2.4*drive)
    const float dc = bias[row] * 2.0f - 1.0f;
    const float mm = mix[row];
    const float om = 1.0f - mm;
    const float c1 = g * 2.8853900817779268f;   // 2*log2(e)*g
    const float c0 = dc * c1;

    const float A2 = alpha * alpha;
    const float A4 = A2 * A2;
    const float A8 = A4 * A4;
    const float A16 = A8 * A8;
    const float A32 = A16 * A16;
    const float A64 = A32 * A32;
    const float A128 = A64 * A64;
    const float A256 = A128 * A128;
    const float A512 = A256 * A256;
    const float A1024 = A512 * A512;

    // per-lane multipliers: p15 = A4^(lane&15), apl = A4^lane
    float p15 = 1.0f;
    {
        float b = A4; const int n = lane & 15;
        #pragma unroll
        for (int i = 0; i < 4; ++i) { if ((n >> i) & 1) p15 *= b; b *= b; }
    }
    const float p31 = (lane & 16) ? p15 * A64  : p15;   // A4^(lane&31)
    const float apl = (lane & 32) ? p31 * A128 : p31;   // A4^lane
    const float w1 = A4 * p15;                          // A4^((lane&15)+1)
    const float w2 = A4 * p31;                          // A4^((lane&31)+1)

    __syncthreads();   // (1) staging visible (drains global_load_lds)

    // ---- halo scan: wave w scans halo sub-block w (256 floats) ----
    // Th parked at sbuf[wv*256] — a slot this wave just finished reading;
    // no other wave reads the halo area, so no race. (bx==0: skipped, carry=0)
    if (bx > 0) {
        const v4f hx = *reinterpret_cast<const v4f*>(&sbuf[wv * 256 + lane * 4]);
        float r = shape(hx.x, ty, g, dc, c1, c0);
        r = fmaf(alpha, r, shape(hx.y, ty, g, dc, c1, c0));
        r = fmaf(alpha, r, shape(hx.z, ty, g, dc, c1, c0));
        r = fmaf(alpha, r, shape(hx.w, ty, g, dc, c1, c0));
        const float s = scan_iir(r, A4, A8, A16, A32, w1, w2);
        if (lane == 63) sbuf[wv * 256] = s;
    }

    // ---- span scans: wave w owns 1024 floats = 4 sub-blocks of 256 ----
    float iv[4], Tk[4];
    #pragma unroll
    for (int k = 0; k < 4; ++k) {
        const v4f xv = *reinterpret_cast<const v4f*>(
            &sbuf[HALO + wv * WSPAN + k * 256 + lane * 4]);
        float acc = shape(xv.x, ty, g, dc, c1, c0);
        acc = fmaf(alpha, acc, shape(xv.y, ty, g, dc, c1, c0));
        acc = fmaf(alpha, acc, shape(xv.z, ty, g, dc, c1, c0));
        acc = fmaf(alpha, acc, shape(xv.w, ty, g, dc, c1, c0));
        iv[k] = scan_iir(acc, A4, A8, A16, A32, w1, w2);
        Tk[k] = readlane_f(iv[k], 63);
    }
    const float Tw =
        fmaf(A256, fmaf(A256, fmaf(A256, Tk[0], Tk[1]), Tk[2]), Tk[3]);
    if (lane == 0) sbuf[wv * 256 + 1] = Tw;   // dead halo slot (own sub-block)
    __syncthreads();   // (2) totals visible; no stores issued yet

    // ---- compose: carry at spanStart, P = z entering this wave's region ----
    float carry = 0.0f;
    if (bx > 0) {
        #pragma unroll
        for (int w = 0; w < WAVES; ++w)
            carry = fmaf(A256, carry, sbuf[w * 256]);
    }
    float P = carry;
    for (int w = 0; w < wv; ++w) P = fmaf(A1024, P, sbuf[w * 256 + 1]);

    // ---- phase C: y[i] = d[i] - beta*z[i-1]; out = om*x + mm*y; stores last ----
    float S = 0.0f, aK = 1.0f;
    #pragma unroll
    for (int k = 0; k < 4; ++k) {
        const int j = spanStart + wv * WSPAN + k * 256 + lane * 4;
        const v4f xv = *reinterpret_cast<const v4f*>(
            &sbuf[HALO + wv * WSPAN + k * 256 + lane * 4]);
        const float d0 = shape(xv.x, ty, g, dc, c1, c0);
        const float d1 = shape(xv.y, ty, g, dc, c1, c0);
        const float d2 = shape(xv.z, ty, g, dc, c1, c0);
        const float d3 = shape(xv.w, ty, g, dc, c1, c0);
        const float Ck = fmaf(aK, P, S);              // z entering sub-block k
        // exclusive lane scan = previous lane's inclusive scan (lane0: 0)
        const float ex = dppf<0x138, 0xF, 0xF, true>(iv[k]); // wave_shr:1
        float z = fmaf(apl, Ck, ex);                  // z before lane's run
        v4f ov; float y;
        y = fmaf(-beta, z, d0); ov.x = fmaf(mm, y, om * xv.x); z = fmaf(alpha, z, d0);
        y = fmaf(-beta, z, d1); ov.y = fmaf(mm, y, om * xv.y); z = fmaf(alpha, z, d1);
        y = fmaf(-beta, z, d2); ov.z = fmaf(mm, y, om * xv.z); z = fmaf(alpha, z, d2);
        y = fmaf(-beta, z, d3); ov.w = fmaf(mm, y, om * xv.w);
        if (j + 4 <= N) {
            __builtin_nontemporal_store(ov, reinterpret_cast<v4f*>(outr + j));
        } else {
            if (j + 0 < N) outr[j + 0] = ov.x;
            if (j + 1 < N) outr[j + 1] = ov.y;
            if (j + 2 < N) outr[j + 2] = ov.z;
            if (j + 3 < N) outr[j + 3] = ov.w;
        }
        S = fmaf(A256, S, Tk[k]);
        aK *= A256;
    }
    // no trailing barrier: stores drain as the block retires
}

extern "C" void kernel_launch(void* const* d_in, const int* in_sizes, int n_in,
                              void* d_out, int out_size, void* d_ws, size_t ws_size,
                              hipStream_t stream) {
    const float* x     = (const float*)d_in[0];
    const float* drive = (const float*)d_in[1];
    const float* bias  = (const float*)d_in[2];
    const float* mixp  = (const float*)d_in[3];
    const int*   tyi   = (const int*)d_in[4];
    float* out = (float*)d_out;

    const int B = in_sizes[1];              // drive is (B,1)
    const int N = in_sizes[0] / B;

    const double alpha_d = exp(-2.0 * M_PI * 20.0 / 44100.0);
    const float alpha = (float)alpha_d;
    const float beta  = (float)(1.0 - alpha_d);

    const int nSpans = (N + SPAN - 1) / SPAN;
    dim3 grid(nSpans, B);
    dist_kernel<<<grid, TPB, 0, stream>>>(x, drive, bias, mixp, tyi, out, N, alpha, beta);
}